// Round 1
// baseline (3039.533 us; speedup 1.0000x reference)
//
#include <hip/hip_runtime.h>
#include <math.h>

#define BATCH 8
#define CIN 512
#define CO 256
#define HW 4096
#define KT 32

// ---------------------------------------------------------------------------
// Kernel 1: proj[b,o,i] = bias[o] + sum_c W[o,c] * x[b,c,i]
// 64x64 tile, 256 threads, 4x4 per thread, K-tiles of 32.
// ---------------------------------------------------------------------------
__global__ __launch_bounds__(256) void k_proj(
    const float* __restrict__ x, const float* __restrict__ W,
    const float* __restrict__ bias, float* __restrict__ proj) {
  __shared__ float As[KT][68];  // [c][o]
  __shared__ float Bs[KT][68];  // [c][i]
  const int i0 = blockIdx.x * 64;
  const int o0 = blockIdx.y * 64;
  const int b  = blockIdx.z;
  const int t  = threadIdx.x;
  const int tx = t & 15, ty = t >> 4;
  const float* xb = x + (size_t)b * CIN * HW;
  float acc[4][4] = {};
  for (int c0 = 0; c0 < CIN; c0 += KT) {
    // W tile -> As[c][o]  (scalar, transposing)
#pragma unroll
    for (int l = 0; l < 8; ++l) {
      int idx = t + l * 256;          // 2048 = 64o x 32c
      int o = idx >> 5;
      int c = idx & 31;
      As[c][o] = W[(size_t)(o0 + o) * CIN + c0 + c];
    }
    // x tile -> Bs[c][i]  (float4, coalesced)
#pragma unroll
    for (int l = 0; l < 2; ++l) {
      int idx4 = t + l * 256;         // 512 float4 = 32c x 16
      int c = idx4 >> 4;
      int i4 = idx4 & 15;
      *(float4*)&Bs[c][i4 * 4] =
          *(const float4*)&xb[(size_t)(c0 + c) * HW + i0 + i4 * 4];
    }
    __syncthreads();
#pragma unroll
    for (int c = 0; c < KT; ++c) {
      float4 a  = *(const float4*)&As[c][tx * 4];
      float4 bv = *(const float4*)&Bs[c][ty * 4];
      float av[4] = {a.x, a.y, a.z, a.w};
      float bb[4] = {bv.x, bv.y, bv.z, bv.w};
#pragma unroll
      for (int u = 0; u < 4; ++u)
#pragma unroll
        for (int v = 0; v < 4; ++v) acc[u][v] += av[u] * bb[v];
    }
    __syncthreads();
  }
  float* pb = proj + (size_t)b * CO * HW;
#pragma unroll
  for (int u = 0; u < 4; ++u) {
    int o = o0 + tx * 4 + u;
    float bs = bias[o];
    float4 r;
    r.x = acc[u][0] + bs; r.y = acc[u][1] + bs;
    r.z = acc[u][2] + bs; r.w = acc[u][3] + bs;
    *(float4*)&pb[(size_t)o * HW + i0 + ty * 4] = r;
  }
}

// ---------------------------------------------------------------------------
// Kernel 2 (pass 1): per-row (x) running max M and sum-exp D over all y.
// S[x,y] = sum_c proj[b,c,x]*pem[b,c,y], K=256. One block per 64 x-rows.
// ---------------------------------------------------------------------------
__global__ __launch_bounds__(256) void k_stats(
    const float* __restrict__ proj, const float* __restrict__ pem,
    float* __restrict__ Mx, float* __restrict__ Dinv) {
  __shared__ float As[KT][68];  // [c][x]
  __shared__ float Bs[KT][68];  // [c][y]
  __shared__ float Ms[64][17];
  __shared__ float Ds[64][17];
  const int x0 = blockIdx.x * 64;
  const int b  = blockIdx.y;
  const int t  = threadIdx.x;
  const int tx = t & 15, ty = t >> 4;
  const float* pj = proj + (size_t)b * CO * HW;
  const float* pe = pem + (size_t)b * CO * HW;
  float m[4], d[4];
#pragma unroll
  for (int u = 0; u < 4; ++u) { m[u] = -3.0e38f; d[u] = 0.f; }

  for (int y0 = 0; y0 < HW; y0 += 64) {
    float s[4][4] = {};
    for (int c0 = 0; c0 < CO; c0 += KT) {
#pragma unroll
      for (int l = 0; l < 2; ++l) {
        int idx4 = t + l * 256;
        int c = idx4 >> 4, w4 = idx4 & 15;
        *(float4*)&As[c][w4 * 4] =
            *(const float4*)&pj[(size_t)(c0 + c) * HW + x0 + w4 * 4];
        *(float4*)&Bs[c][w4 * 4] =
            *(const float4*)&pe[(size_t)(c0 + c) * HW + y0 + w4 * 4];
      }
      __syncthreads();
#pragma unroll
      for (int c = 0; c < KT; ++c) {
        float4 a  = *(const float4*)&As[c][tx * 4];
        float4 bv = *(const float4*)&Bs[c][ty * 4];
        float av[4] = {a.x, a.y, a.z, a.w};
        float bb[4] = {bv.x, bv.y, bv.z, bv.w};
#pragma unroll
        for (int u = 0; u < 4; ++u)
#pragma unroll
          for (int v = 0; v < 4; ++v) s[u][v] += av[u] * bb[v];
      }
      __syncthreads();
    }
    // online max/sumexp update for this thread's 4 rows x 4-col slice
#pragma unroll
    for (int u = 0; u < 4; ++u) {
      float mv = fmaxf(fmaxf(s[u][0], s[u][1]), fmaxf(s[u][2], s[u][3]));
      if (mv > m[u]) { d[u] *= __expf(m[u] - mv); m[u] = mv; }
      d[u] += __expf(s[u][0] - m[u]) + __expf(s[u][1] - m[u]) +
              __expf(s[u][2] - m[u]) + __expf(s[u][3] - m[u]);
    }
  }
  // combine 16 (m,d) partials per row across ty
#pragma unroll
  for (int u = 0; u < 4; ++u) { Ms[tx * 4 + u][ty] = m[u]; Ds[tx * 4 + u][ty] = d[u]; }
  __syncthreads();
  if (t < 64) {
    float mm = -3.0e38f;
#pragma unroll
    for (int i = 0; i < 16; ++i) mm = fmaxf(mm, Ms[t][i]);
    float dd = 0.f;
#pragma unroll
    for (int i = 0; i < 16; ++i) dd += Ds[t][i] * __expf(Ms[t][i] - mm);
    Mx[(size_t)b * HW + x0 + t]   = mm;
    Dinv[(size_t)b * HW + x0 + t] = 1.0f / dd;
  }
}

// ---------------------------------------------------------------------------
// Kernel 3 (pass 2): out[b,k,y] = sum_x pem[b,k,x] * exp(S[x,y]-M[x])*Dinv[x]
// One block per (b, 64-y block). Loops over x in 64-chunks:
//   phase A: recompute S chunk [64x][64y], apply exp -> E in LDS
//   phase B: acc[256k][64y] += pem[:,xchunk] @ E   (8k x 8y per thread)
// ---------------------------------------------------------------------------
__global__ __launch_bounds__(256) void k_out(
    const float* __restrict__ proj, const float* __restrict__ pem,
    const float* __restrict__ Mx, const float* __restrict__ Dinv,
    float* __restrict__ out) {
  __shared__ float As[KT][68];  // [c][x]
  __shared__ float Bs[KT][68];  // [c][y]
  __shared__ float E[64][68];   // [x][y]
  const int y0 = blockIdx.x * 64;
  const int b  = blockIdx.y;
  const int t  = threadIdx.x;
  const int tx = t & 15, ty = t >> 4;   // phase A mapping
  const int kg = t >> 3, yg = t & 7;    // phase B mapping: 8k x 8y per thread
  const float* pj = proj + (size_t)b * CO * HW;
  const float* pe = pem + (size_t)b * CO * HW;
  const float* Mb = Mx + (size_t)b * HW;
  const float* Db = Dinv + (size_t)b * HW;
  float acc[8][8] = {};

  for (int x0 = 0; x0 < HW; x0 += 64) {
    // ---- phase A: S chunk ----
    float s[4][4] = {};
    for (int c0 = 0; c0 < CO; c0 += KT) {
#pragma unroll
      for (int l = 0; l < 2; ++l) {
        int idx4 = t + l * 256;
        int c = idx4 >> 4, w4 = idx4 & 15;
        *(float4*)&As[c][w4 * 4] =
            *(const float4*)&pj[(size_t)(c0 + c) * HW + x0 + w4 * 4];
        *(float4*)&Bs[c][w4 * 4] =
            *(const float4*)&pe[(size_t)(c0 + c) * HW + y0 + w4 * 4];
      }
      __syncthreads();
#pragma unroll
      for (int c = 0; c < KT; ++c) {
        float4 a  = *(const float4*)&As[c][tx * 4];
        float4 bv = *(const float4*)&Bs[c][ty * 4];
        float av[4] = {a.x, a.y, a.z, a.w};
        float bb[4] = {bv.x, bv.y, bv.z, bv.w};
#pragma unroll
        for (int u = 0; u < 4; ++u)
#pragma unroll
          for (int v = 0; v < 4; ++v) s[u][v] += av[u] * bb[v];
      }
      __syncthreads();
    }
    // E = exp(S - M[x]) * Dinv[x]
#pragma unroll
    for (int u = 0; u < 4; ++u) {
      int xr = x0 + tx * 4 + u;
      float mm = Mb[xr];
      float di = Db[xr];
      E[tx * 4 + u][ty * 4 + 0] = __expf(s[u][0] - mm) * di;
      E[tx * 4 + u][ty * 4 + 1] = __expf(s[u][1] - mm) * di;
      E[tx * 4 + u][ty * 4 + 2] = __expf(s[u][2] - mm) * di;
      E[tx * 4 + u][ty * 4 + 3] = __expf(s[u][3] - mm) * di;
    }
    __syncthreads();
    // ---- phase B: acc += pem[:,xchunk] @ E ----
    for (int xi = 0; xi < 64; xi += 4) {
      float4 p[8];
#pragma unroll
      for (int u = 0; u < 8; ++u)
        p[u] = *(const float4*)&pe[(size_t)(kg * 8 + u) * HW + x0 + xi];
#pragma unroll
      for (int j = 0; j < 4; ++j) {
        float4 e0 = *(const float4*)&E[xi + j][yg * 8];
        float4 e1 = *(const float4*)&E[xi + j][yg * 8 + 4];
        float ev[8] = {e0.x, e0.y, e0.z, e0.w, e1.x, e1.y, e1.z, e1.w};
#pragma unroll
        for (int u = 0; u < 8; ++u) {
          float a = (j == 0) ? p[u].x : (j == 1) ? p[u].y : (j == 2) ? p[u].z : p[u].w;
#pragma unroll
          for (int v = 0; v < 8; ++v) acc[u][v] += a * ev[v];
        }
      }
    }
    __syncthreads();
  }
  // write out tile
#pragma unroll
  for (int u = 0; u < 8; ++u) {
    int k = kg * 8 + u;
    float4 r0, r1;
    r0.x = acc[u][0]; r0.y = acc[u][1]; r0.z = acc[u][2]; r0.w = acc[u][3];
    r1.x = acc[u][4]; r1.y = acc[u][5]; r1.z = acc[u][6]; r1.w = acc[u][7];
    float* ob = out + ((size_t)b * CO + k) * HW + y0 + yg * 8;
    *(float4*)&ob[0] = r0;
    *(float4*)&ob[4] = r1;
  }
}

// ---------------------------------------------------------------------------
extern "C" void kernel_launch(void* const* d_in, const int* in_sizes, int n_in,
                              void* d_out, int out_size, void* d_ws, size_t ws_size,
                              hipStream_t stream) {
  const float* x    = (const float*)d_in[0];
  const float* pem  = (const float*)d_in[1];
  const float* W    = (const float*)d_in[2];
  const float* bias = (const float*)d_in[3];
  float* out = (float*)d_out;

  const size_t projElems = (size_t)BATCH * CO * HW;      // 8.39M floats
  float* proj = (float*)d_ws;
  float* Mx   = proj + projElems;
  float* Dinv = Mx + (size_t)BATCH * HW;
  const size_t need = (projElems + 2 * (size_t)BATCH * HW) * sizeof(float);
  if (ws_size < need) return;  // ws too small: fail loudly rather than corrupt

  k_proj <<<dim3(HW / 64, CO / 64, BATCH), 256, 0, stream>>>(x, W, bias, proj);
  k_stats<<<dim3(HW / 64, BATCH),          256, 0, stream>>>(proj, pem, Mx, Dinv);
  k_out  <<<dim3(HW / 64, BATCH),          256, 0, stream>>>(proj, pem, Mx, Dinv, out);
}

// Round 2
// 985.338 us; speedup vs baseline: 3.0848x; 3.0848x over previous
//
#include <hip/hip_runtime.h>
#include <math.h>

#define BATCH 8
#define CIN 512
#define CO 256
#define HW 4096
#define KT 32

typedef unsigned short ushort_t;
typedef unsigned int uint_t;
typedef __bf16 v8bf __attribute__((ext_vector_type(8)));
typedef float v4f __attribute__((ext_vector_type(4)));

__device__ __forceinline__ ushort_t f2bf(float f) {
  uint_t u = __float_as_uint(f);
  u += 0x7FFFu + ((u >> 16) & 1u);   // round-to-nearest-even
  return (ushort_t)(u >> 16);
}
__device__ __forceinline__ float bf2f(ushort_t h) {
  return __uint_as_float(((uint_t)h) << 16);
}
__device__ __forceinline__ v4f mfma16(v8bf a, v8bf b, v4f c) {
  return __builtin_amdgcn_mfma_f32_16x16x32_bf16(a, b, c, 0, 0, 0);
}
// LDS tile read: row-major, `pitch` bytes/row, 16B granules XOR-swizzled by (row&7)
__device__ __forceinline__ v8bf lds_frag(const unsigned char* base, int row, int cb, int pitch) {
  uint4 v = *(const uint4*)(base + (size_t)row * pitch + (((cb) ^ (row & 7)) << 4));
  return __builtin_bit_cast(v8bf, v);
}

// ===========================================================================
// MFMA path
// ===========================================================================

// proj = W@x + bias (fp32 VALU), output split-bf16 transposed: proj_t[b][x][c]
__global__ __launch_bounds__(256) void k_proj_split(
    const float* __restrict__ x, const float* __restrict__ W,
    const float* __restrict__ bias,
    ushort_t* __restrict__ proj_hi, ushort_t* __restrict__ proj_lo) {
  __shared__ float As[KT][68];  // [c][o]
  __shared__ float Bs[KT][68];  // [c][i]
  const int i0 = blockIdx.x * 64;
  const int o0 = blockIdx.y * 64;
  const int b  = blockIdx.z;
  const int t  = threadIdx.x;
  const int tx = t & 15, ty = t >> 4;
  const float* xb = x + (size_t)b * CIN * HW;
  float acc[4][4] = {};
  for (int c0 = 0; c0 < CIN; c0 += KT) {
#pragma unroll
    for (int l = 0; l < 8; ++l) {
      int idx = t + l * 256;
      int o = idx >> 5;
      int c = idx & 31;
      As[c][o] = W[(size_t)(o0 + o) * CIN + c0 + c];
    }
#pragma unroll
    for (int l = 0; l < 2; ++l) {
      int idx4 = t + l * 256;
      int c = idx4 >> 4;
      int i4 = idx4 & 15;
      *(float4*)&Bs[c][i4 * 4] =
          *(const float4*)&xb[(size_t)(c0 + c) * HW + i0 + i4 * 4];
    }
    __syncthreads();
#pragma unroll
    for (int c = 0; c < KT; ++c) {
      float4 a  = *(const float4*)&As[c][tx * 4];
      float4 bv = *(const float4*)&Bs[c][ty * 4];
      float av[4] = {a.x, a.y, a.z, a.w};
      float bb[4] = {bv.x, bv.y, bv.z, bv.w};
#pragma unroll
      for (int u = 0; u < 4; ++u)
#pragma unroll
        for (int v = 0; v < 4; ++v) acc[u][v] += av[u] * bb[v];
    }
    __syncthreads();
  }
  float bs[4];
#pragma unroll
  for (int u = 0; u < 4; ++u) bs[u] = bias[o0 + tx * 4 + u];
#pragma unroll
  for (int v = 0; v < 4; ++v) {
    int xx = i0 + ty * 4 + v;
    ushort4 hi, lo;
    float z0 = acc[0][v] + bs[0];
    float z1 = acc[1][v] + bs[1];
    float z2 = acc[2][v] + bs[2];
    float z3 = acc[3][v] + bs[3];
    hi.x = f2bf(z0); hi.y = f2bf(z1); hi.z = f2bf(z2); hi.w = f2bf(z3);
    lo.x = f2bf(z0 - bf2f(hi.x)); lo.y = f2bf(z1 - bf2f(hi.y));
    lo.z = f2bf(z2 - bf2f(hi.z)); lo.w = f2bf(z3 - bf2f(hi.w));
    size_t off = ((size_t)b * HW + xx) * CO + o0 + tx * 4;
    *(ushort4*)&proj_hi[off] = hi;
    *(ushort4*)&proj_lo[off] = lo;
  }
}

// pem [b][c][y] fp32 -> pem_t[b][y][c] hi/lo bf16 (transposed)  and
//                       pem_kx[b][c][y] hi bf16 (same layout)
__global__ __launch_bounds__(256) void k_tr_pem(
    const float* __restrict__ pem,
    ushort_t* __restrict__ pem_t_hi, ushort_t* __restrict__ pem_t_lo,
    ushort_t* __restrict__ pem_kx) {
  __shared__ float T[64][65];
  const int y0 = blockIdx.x * 64;
  const int c0 = blockIdx.y * 64;
  const int b  = blockIdx.z;
  const int t  = threadIdx.x;
  const int cl = t >> 4;
  const int y4 = (t & 15) * 4;
#pragma unroll
  for (int r = 0; r < 4; ++r) {
    int c = c0 + r * 16 + cl;
    size_t off = ((size_t)b * CO + c) * HW + y0 + y4;
    float4 v = *(const float4*)&pem[off];
    ushort4 h;
    h.x = f2bf(v.x); h.y = f2bf(v.y); h.z = f2bf(v.z); h.w = f2bf(v.w);
    *(ushort4*)&pem_kx[off] = h;
    T[r * 16 + cl][y4 + 0] = v.x;
    T[r * 16 + cl][y4 + 1] = v.y;
    T[r * 16 + cl][y4 + 2] = v.z;
    T[r * 16 + cl][y4 + 3] = v.w;
  }
  __syncthreads();
  const int yl = t >> 2;
  const int cq = (t & 3) * 16;
  size_t rowoff = ((size_t)b * HW + y0 + yl) * CO + c0 + cq;
#pragma unroll
  for (int j4 = 0; j4 < 4; ++j4) {
    ushort4 h, l;
    float f0 = T[cq + j4 * 4 + 0][yl];
    float f1 = T[cq + j4 * 4 + 1][yl];
    float f2 = T[cq + j4 * 4 + 2][yl];
    float f3 = T[cq + j4 * 4 + 3][yl];
    h.x = f2bf(f0); h.y = f2bf(f1); h.z = f2bf(f2); h.w = f2bf(f3);
    l.x = f2bf(f0 - bf2f(h.x)); l.y = f2bf(f1 - bf2f(h.y));
    l.z = f2bf(f2 - bf2f(h.z)); l.w = f2bf(f3 - bf2f(h.w));
    *(ushort4*)&pem_t_hi[rowoff + j4 * 4] = h;
    *(ushort4*)&pem_t_lo[rowoff + j4 * 4] = l;
  }
}

// pass 1: row stats M[x], Dinv[x].  S via split-bf16 MFMA.
// block: 512 thr (8 waves, 4 wx x 2 wy), x-tile 64 resident, y loop in 64-tiles.
__global__ __launch_bounds__(512) void k_stats_mfma(
    const ushort_t* __restrict__ proj_hi, const ushort_t* __restrict__ proj_lo,
    const ushort_t* __restrict__ pem_t_hi, const ushort_t* __restrict__ pem_t_lo,
    float* __restrict__ Mx, float* __restrict__ Dinv) {
  __shared__ __align__(16) unsigned char pa[2 * 64 * 512];  // proj x-tile hi|lo
  __shared__ __align__(16) unsigned char pb[2 * 64 * 512];  // pem_t y-tile hi|lo
  const int bid = blockIdx.x;
  const int b = bid & 7, x0 = (bid >> 3) * 64;   // b -> XCD pinning
  const int t = threadIdx.x;
  const int lane = t & 63, wave = t >> 6;
  const int wx = wave >> 1, wy = wave & 1;
  // stage pa once
  {
    const ushort_t* s1 = proj_hi + ((size_t)b * HW + x0) * CO;
    const ushort_t* s2 = proj_lo + ((size_t)b * HW + x0) * CO;
#pragma unroll
    for (int i = 0; i < 4; ++i) {
      int g = i * 512 + t;
      int r = g >> 5, sl = g & 31;
      *(uint4*)(pa + r * 512 + ((sl ^ (r & 7)) << 4)) =
          *(const uint4*)(s1 + (size_t)r * CO + sl * 8);
      *(uint4*)(pa + 64 * 512 + r * 512 + ((sl ^ (r & 7)) << 4)) =
          *(const uint4*)(s2 + (size_t)r * CO + sl * 8);
    }
  }
  float m[4], dsum[4];
#pragma unroll
  for (int r = 0; r < 4; ++r) { m[r] = -3.0e38f; dsum[r] = 0.f; }

  const int ar  = wx * 16 + (lane & 15);
  const int br0 = wy * 32 + (lane & 15);
  const int br1 = br0 + 16;

  for (int y0 = 0; y0 < HW; y0 += 64) {
    __syncthreads();  // prev iter done with pb (covers pa stage on iter 0)
    const ushort_t* s1 = pem_t_hi + ((size_t)b * HW + y0) * CO;
    const ushort_t* s2 = pem_t_lo + ((size_t)b * HW + y0) * CO;
#pragma unroll
    for (int i = 0; i < 4; ++i) {
      int g = i * 512 + t;
      int r = g >> 5, sl = g & 31;
      *(uint4*)(pb + r * 512 + ((sl ^ (r & 7)) << 4)) =
          *(const uint4*)(s1 + (size_t)r * CO + sl * 8);
      *(uint4*)(pb + 64 * 512 + r * 512 + ((sl ^ (r & 7)) << 4)) =
          *(const uint4*)(s2 + (size_t)r * CO + sl * 8);
    }
    __syncthreads();
    v4f acc0 = {0.f, 0.f, 0.f, 0.f}, acc1 = {0.f, 0.f, 0.f, 0.f};
#pragma unroll
    for (int cs = 0; cs < 8; ++cs) {
      int cb = cs * 4 + (lane >> 4);
      v8bf ah  = lds_frag(pa, ar, cb, 512);
      v8bf al  = lds_frag(pa + 64 * 512, ar, cb, 512);
      v8bf bh0 = lds_frag(pb, br0, cb, 512);
      v8bf bl0 = lds_frag(pb + 64 * 512, br0, cb, 512);
      v8bf bh1 = lds_frag(pb, br1, cb, 512);
      v8bf bl1 = lds_frag(pb + 64 * 512, br1, cb, 512);
      acc0 = mfma16(ah, bh0, acc0);
      acc0 = mfma16(ah, bl0, acc0);
      acc0 = mfma16(al, bh0, acc0);
      acc1 = mfma16(ah, bh1, acc1);
      acc1 = mfma16(ah, bl1, acc1);
      acc1 = mfma16(al, bh1, acc1);
    }
    // online stats; the 16 lanes sharing a row set are lanes differing in low4
#pragma unroll
    for (int r = 0; r < 4; ++r) {
      float mx = fmaxf(acc0[r], acc1[r]);
      mx = fmaxf(mx, __shfl_xor(mx, 1));
      mx = fmaxf(mx, __shfl_xor(mx, 2));
      mx = fmaxf(mx, __shfl_xor(mx, 4));
      mx = fmaxf(mx, __shfl_xor(mx, 8));
      if (mx > m[r]) { dsum[r] *= __expf(m[r] - mx); m[r] = mx; }
      float e = __expf(acc0[r] - m[r]) + __expf(acc1[r] - m[r]);
      e += __shfl_xor(e, 1);
      e += __shfl_xor(e, 2);
      e += __shfl_xor(e, 4);
      e += __shfl_xor(e, 8);
      dsum[r] += e;
    }
  }
  __syncthreads();
  float* redm = (float*)pb;            // [64][2]
  float* redd = (float*)(pb + 4096);
  if ((lane & 15) == 0) {
#pragma unroll
    for (int r = 0; r < 4; ++r) {
      int xr = wx * 16 + (lane >> 4) * 4 + r;
      redm[xr * 2 + wy] = m[r];
      redd[xr * 2 + wy] = dsum[r];
    }
  }
  __syncthreads();
  if (t < 64) {
    float m0 = redm[t * 2], m1 = redm[t * 2 + 1];
    float mm = fmaxf(m0, m1);
    float dd = redd[t * 2] * __expf(m0 - mm) + redd[t * 2 + 1] * __expf(m1 - mm);
    Mx[(size_t)b * HW + x0 + t] = mm;
    Dinv[(size_t)b * HW + x0 + t] = 1.0f / dd;
  }
}

// pass 2: out[b,k,y] = sum_x pem[k,x] * exp(S[x,y]-M[x])*Dinv[x]
// block: 512 thr, y-tile 64 resident (pb), x loop in 64-chunks.
// U1 union: phase A = proj x-tile hi|lo (64KB); phase B = pem_kx tile (32KB).
__global__ __launch_bounds__(512) void k_out_mfma(
    const ushort_t* __restrict__ proj_hi, const ushort_t* __restrict__ proj_lo,
    const ushort_t* __restrict__ pem_t_hi, const ushort_t* __restrict__ pem_t_lo,
    const ushort_t* __restrict__ pem_kx,
    const float* __restrict__ Mx, const float* __restrict__ Dinv,
    float* __restrict__ out) {
  __shared__ __align__(16) unsigned char pb[2 * 64 * 512];
  __shared__ __align__(16) unsigned char U1[2 * 64 * 512];
  __shared__ __align__(16) unsigned char Elds[64 * 128];
  __shared__ float Ms[64], Ds[64];
  const int bid = blockIdx.x;
  const int b = bid & 7, y0 = (bid >> 3) * 64;
  const int t = threadIdx.x;
  const int lane = t & 63, wave = t >> 6;
  const int wx = wave >> 1, wy = wave & 1;
  // stage pb once
  {
    const ushort_t* s1 = pem_t_hi + ((size_t)b * HW + y0) * CO;
    const ushort_t* s2 = pem_t_lo + ((size_t)b * HW + y0) * CO;
#pragma unroll
    for (int i = 0; i < 4; ++i) {
      int g = i * 512 + t;
      int r = g >> 5, sl = g & 31;
      *(uint4*)(pb + r * 512 + ((sl ^ (r & 7)) << 4)) =
          *(const uint4*)(s1 + (size_t)r * CO + sl * 8);
      *(uint4*)(pb + 64 * 512 + r * 512 + ((sl ^ (r & 7)) << 4)) =
          *(const uint4*)(s2 + (size_t)r * CO + sl * 8);
    }
  }
  v4f oacc[2][4];
#pragma unroll
  for (int kf = 0; kf < 2; ++kf)
#pragma unroll
    for (int yf = 0; yf < 4; ++yf) oacc[kf][yf] = (v4f){0.f, 0.f, 0.f, 0.f};

  const int ar  = wx * 16 + (lane & 15);
  const int br0 = wy * 32 + (lane & 15);
  const int br1 = br0 + 16;
  const int kb  = wave * 32;

  for (int x0 = 0; x0 < HW; x0 += 64) {
    __syncthreads();  // prev PV done with U1/Elds (covers pb stage on iter 0)
    {
      const ushort_t* s1 = proj_hi + ((size_t)b * HW + x0) * CO;
      const ushort_t* s2 = proj_lo + ((size_t)b * HW + x0) * CO;
#pragma unroll
      for (int i = 0; i < 4; ++i) {
        int g = i * 512 + t;
        int r = g >> 5, sl = g & 31;
        *(uint4*)(U1 + r * 512 + ((sl ^ (r & 7)) << 4)) =
            *(const uint4*)(s1 + (size_t)r * CO + sl * 8);
        *(uint4*)(U1 + 64 * 512 + r * 512 + ((sl ^ (r & 7)) << 4)) =
            *(const uint4*)(s2 + (size_t)r * CO + sl * 8);
      }
      if (t < 64) Ms[t] = Mx[(size_t)b * HW + x0 + t];
      else if (t < 128) Ds[t - 64] = Dinv[(size_t)b * HW + x0 + t - 64];
    }
    __syncthreads();
    // ---- phase A: S tile (split-bf16 MFMA) ----
    v4f s0 = {0.f, 0.f, 0.f, 0.f}, s1v = {0.f, 0.f, 0.f, 0.f};
#pragma unroll
    for (int cs = 0; cs < 8; ++cs) {
      int cb = cs * 4 + (lane >> 4);
      v8bf ah  = lds_frag(U1, ar, cb, 512);
      v8bf al  = lds_frag(U1 + 64 * 512, ar, cb, 512);
      v8bf bh0 = lds_frag(pb, br0, cb, 512);
      v8bf bl0 = lds_frag(pb + 64 * 512, br0, cb, 512);
      v8bf bh1 = lds_frag(pb, br1, cb, 512);
      v8bf bl1 = lds_frag(pb + 64 * 512, br1, cb, 512);
      s0  = mfma16(ah, bh0, s0);
      s0  = mfma16(ah, bl0, s0);
      s0  = mfma16(al, bh0, s0);
      s1v = mfma16(ah, bh1, s1v);
      s1v = mfma16(ah, bl1, s1v);
      s1v = mfma16(al, bh1, s1v);
    }
    // ---- E = exp(S-M)*Dinv -> bf16 -> Elds[y][x] (swizzled, pitch 128B) ----
    {
      int xl0 = wx * 16 + (lane >> 4) * 4;
      float mv0 = Ms[xl0], mv1 = Ms[xl0 + 1], mv2 = Ms[xl0 + 2], mv3 = Ms[xl0 + 3];
      float dv0 = Ds[xl0], dv1 = Ds[xl0 + 1], dv2 = Ds[xl0 + 2], dv3 = Ds[xl0 + 3];
      int gx = xl0 >> 3;
      int off8 = (xl0 & 7) * 2;
      int yl0 = wy * 32 + (lane & 15);
      int yl1 = yl0 + 16;
      ushort4 p0, p1;
      p0.x = f2bf(__expf(s0[0] - mv0) * dv0);
      p0.y = f2bf(__expf(s0[1] - mv1) * dv1);
      p0.z = f2bf(__expf(s0[2] - mv2) * dv2);
      p0.w = f2bf(__expf(s0[3] - mv3) * dv3);
      p1.x = f2bf(__expf(s1v[0] - mv0) * dv0);
      p1.y = f2bf(__expf(s1v[1] - mv1) * dv1);
      p1.z = f2bf(__expf(s1v[2] - mv2) * dv2);
      p1.w = f2bf(__expf(s1v[3] - mv3) * dv3);
      *(ushort4*)(Elds + yl0 * 128 + ((gx ^ (yl0 & 7)) << 4) + off8) = p0;
      *(ushort4*)(Elds + yl1 * 128 + ((gx ^ (yl1 & 7)) << 4) + off8) = p1;
    }
    __syncthreads();  // E visible; pa reads done -> U1 reusable
    // ---- stage pem_kx tile [256k][64x] into U1 ----
    {
      const ushort_t* s3 = pem_kx + (size_t)b * CO * HW + x0;
#pragma unroll
      for (int i = 0; i < 4; ++i) {
        int g = i * 512 + t;
        int r = g >> 3, sl = g & 7;
        *(uint4*)(U1 + r * 128 + ((sl ^ (r & 7)) << 4)) =
            *(const uint4*)(s3 + (size_t)r * HW + sl * 8);
      }
    }
    __syncthreads();
    // ---- phase B: PV ----
#pragma unroll
    for (int cs = 0; cs < 2; ++cs) {
      int cb = cs * 4 + (lane >> 4);
      v8bf a0 = lds_frag(U1, kb + (lane & 15), cb, 128);
      v8bf a1 = lds_frag(U1, kb + 16 + (lane & 15), cb, 128);
      v8bf e0 = lds_frag(Elds, 0 + (lane & 15), cb, 128);
      v8bf e1 = lds_frag(Elds, 16 + (lane & 15), cb, 128);
      v8bf e2 = lds_frag(Elds, 32 + (lane & 15), cb, 128);
      v8bf e3 = lds_frag(Elds, 48 + (lane & 15), cb, 128);
      oacc[0][0] = mfma16(a0, e0, oacc[0][0]);
      oacc[0][1] = mfma16(a0, e1, oacc[0][1]);
      oacc[0][2] = mfma16(a0, e2, oacc[0][2]);
      oacc[0][3] = mfma16(a0, e3, oacc[0][3]);
      oacc[1][0] = mfma16(a1, e0, oacc[1][0]);
      oacc[1][1] = mfma16(a1, e1, oacc[1][1]);
      oacc[1][2] = mfma16(a1, e2, oacc[1][2]);
      oacc[1][3] = mfma16(a1, e3, oacc[1][3]);
    }
  }
  // epilogue
#pragma unroll
  for (int kf = 0; kf < 2; ++kf) {
#pragma unroll
    for (int yf = 0; yf < 4; ++yf) {
#pragma unroll
      for (int r = 0; r < 4; ++r) {
        int k = kb + kf * 16 + (lane >> 4) * 4 + r;
        int y = y0 + yf * 16 + (lane & 15);
        out[((size_t)b * CO + k) * HW + y] = oacc[kf][yf][r];
      }
    }
  }
}

// ===========================================================================
// fp32 fallback path (round-1 kernels, used only if ws is too small)
// ===========================================================================
__global__ __launch_bounds__(256) void k_proj(
    const float* __restrict__ x, const float* __restrict__ W,
    const float* __restrict__ bias, float* __restrict__ proj) {
  __shared__ float As[KT][68];
  __shared__ float Bs[KT][68];
  const int i0 = blockIdx.x * 64;
  const int o0 = blockIdx.y * 64;
  const int b  = blockIdx.z;
  const int t  = threadIdx.x;
  const int tx = t & 15, ty = t >> 4;
  const float* xb = x + (size_t)b * CIN * HW;
  float acc[4][4] = {};
  for (int c0 = 0; c0 < CIN; c0 += KT) {
#pragma unroll
    for (int l = 0; l < 8; ++l) {
      int idx = t + l * 256;
      int o = idx >> 5;
      int c = idx & 31;
      As[c][o] = W[(size_t)(o0 + o) * CIN + c0 + c];
    }
#pragma unroll
    for (int l = 0; l < 2; ++l) {
      int idx4 = t + l * 256;
      int c = idx4 >> 4;
      int i4 = idx4 & 15;
      *(float4*)&Bs[c][i4 * 4] =
          *(const float4*)&xb[(size_t)(c0 + c) * HW + i0 + i4 * 4];
    }
    __syncthreads();
#pragma unroll
    for (int c = 0; c < KT; ++c) {
      float4 a  = *(const float4*)&As[c][tx * 4];
      float4 bv = *(const float4*)&Bs[c][ty * 4];
      float av[4] = {a.x, a.y, a.z, a.w};
      float bb[4] = {bv.x, bv.y, bv.z, bv.w};
#pragma unroll
      for (int u = 0; u < 4; ++u)
#pragma unroll
        for (int v = 0; v < 4; ++v) acc[u][v] += av[u] * bb[v];
    }
    __syncthreads();
  }
  float* pbout = proj + (size_t)b * CO * HW;
#pragma unroll
  for (int u = 0; u < 4; ++u) {
    int o = o0 + tx * 4 + u;
    float bsv = bias[o];
    float4 r;
    r.x = acc[u][0] + bsv; r.y = acc[u][1] + bsv;
    r.z = acc[u][2] + bsv; r.w = acc[u][3] + bsv;
    *(float4*)&pbout[(size_t)o * HW + i0 + ty * 4] = r;
  }
}

__global__ __launch_bounds__(256) void k_stats(
    const float* __restrict__ proj, const float* __restrict__ pem,
    float* __restrict__ Mx, float* __restrict__ Dinv) {
  __shared__ float As[KT][68];
  __shared__ float Bs[KT][68];
  __shared__ float MsS[64][17];
  __shared__ float DsS[64][17];
  const int x0 = blockIdx.x * 64;
  const int b  = blockIdx.y;
  const int t  = threadIdx.x;
  const int tx = t & 15, ty = t >> 4;
  const float* pj = proj + (size_t)b * CO * HW;
  const float* pe = pem + (size_t)b * CO * HW;
  float m[4], d[4];
#pragma unroll
  for (int u = 0; u < 4; ++u) { m[u] = -3.0e38f; d[u] = 0.f; }
  for (int y0 = 0; y0 < HW; y0 += 64) {
    float s[4][4] = {};
    for (int c0 = 0; c0 < CO; c0 += KT) {
#pragma unroll
      for (int l = 0; l < 2; ++l) {
        int idx4 = t + l * 256;
        int c = idx4 >> 4, w4 = idx4 & 15;
        *(float4*)&As[c][w4 * 4] =
            *(const float4*)&pj[(size_t)(c0 + c) * HW + x0 + w4 * 4];
        *(float4*)&Bs[c][w4 * 4] =
            *(const float4*)&pe[(size_t)(c0 + c) * HW + y0 + w4 * 4];
      }
      __syncthreads();
#pragma unroll
      for (int c = 0; c < KT; ++c) {
        float4 a  = *(const float4*)&As[c][tx * 4];
        float4 bv = *(const float4*)&Bs[c][ty * 4];
        float av[4] = {a.x, a.y, a.z, a.w};
        float bb[4] = {bv.x, bv.y, bv.z, bv.w};
#pragma unroll
        for (int u = 0; u < 4; ++u)
#pragma unroll
          for (int v = 0; v < 4; ++v) s[u][v] += av[u] * bb[v];
      }
      __syncthreads();
    }
#pragma unroll
    for (int u = 0; u < 4; ++u) {
      float mv = fmaxf(fmaxf(s[u][0], s[u][1]), fmaxf(s[u][2], s[u][3]));
      if (mv > m[u]) { d[u] *= __expf(m[u] - mv); m[u] = mv; }
      d[u] += __expf(s[u][0] - m[u]) + __expf(s[u][1] - m[u]) +
              __expf(s[u][2] - m[u]) + __expf(s[u][3] - m[u]);
    }
  }
#pragma unroll
  for (int u = 0; u < 4; ++u) { MsS[tx * 4 + u][ty] = m[u]; DsS[tx * 4 + u][ty] = d[u]; }
  __syncthreads();
  if (t < 64) {
    float mm = -3.0e38f;
#pragma unroll
    for (int i = 0; i < 16; ++i) mm = fmaxf(mm, MsS[t][i]);
    float dd = 0.f;
#pragma unroll
    for (int i = 0; i < 16; ++i) dd += DsS[t][i] * __expf(MsS[t][i] - mm);
    Mx[(size_t)b * HW + x0 + t]   = mm;
    Dinv[(size_t)b * HW + x0 + t] = 1.0f / dd;
  }
}

__global__ __launch_bounds__(256) void k_out(
    const float* __restrict__ proj, const float* __restrict__ pem,
    const float* __restrict__ Mx, const float* __restrict__ Dinv,
    float* __restrict__ out) {
  __shared__ float As[KT][68];
  __shared__ float Bs[KT][68];
  __shared__ float E[64][68];
  const int y0 = blockIdx.x * 64;
  const int b  = blockIdx.y;
  const int t  = threadIdx.x;
  const int tx = t & 15, ty = t >> 4;
  const int kg = t >> 3, yg = t & 7;
  const float* pj = proj + (size_t)b * CO * HW;
  const float* pe = pem + (size_t)b * CO * HW;
  const float* Mb = Mx + (size_t)b * HW;
  const float* Db = Dinv + (size_t)b * HW;
  float acc[8][8] = {};
  for (int x0 = 0; x0 < HW; x0 += 64) {
    float s[4][4] = {};
    for (int c0 = 0; c0 < CO; c0 += KT) {
#pragma unroll
      for (int l = 0; l < 2; ++l) {
        int idx4 = t + l * 256;
        int c = idx4 >> 4, w4 = idx4 & 15;
        *(float4*)&As[c][w4 * 4] =
            *(const float4*)&pj[(size_t)(c0 + c) * HW + x0 + w4 * 4];
        *(float4*)&Bs[c][w4 * 4] =
            *(const float4*)&pe[(size_t)(c0 + c) * HW + y0 + w4 * 4];
      }
      __syncthreads();
#pragma unroll
      for (int c = 0; c < KT; ++c) {
        float4 a  = *(const float4*)&As[c][tx * 4];
        float4 bv = *(const float4*)&Bs[c][ty * 4];
        float av[4] = {a.x, a.y, a.z, a.w};
        float bb[4] = {bv.x, bv.y, bv.z, bv.w};
#pragma unroll
        for (int u = 0; u < 4; ++u)
#pragma unroll
          for (int v = 0; v < 4; ++v) s[u][v] += av[u] * bb[v];
      }
      __syncthreads();
    }
#pragma unroll
    for (int u = 0; u < 4; ++u) {
      int xr = x0 + tx * 4 + u;
      float mm = Mb[xr];
      float di = Db[xr];
      E[tx * 4 + u][ty * 4 + 0] = __expf(s[u][0] - mm) * di;
      E[tx * 4 + u][ty * 4 + 1] = __expf(s[u][1] - mm) * di;
      E[tx * 4 + u][ty * 4 + 2] = __expf(s[u][2] - mm) * di;
      E[tx * 4 + u][ty * 4 + 3] = __expf(s[u][3] - mm) * di;
    }
    __syncthreads();
    for (int xi = 0; xi < 64; xi += 4) {
      float4 p[8];
#pragma unroll
      for (int u = 0; u < 8; ++u)
        p[u] = *(const float4*)&pe[(size_t)(kg * 8 + u) * HW + x0 + xi];
#pragma unroll
      for (int j = 0; j < 4; ++j) {
        float4 e0 = *(const float4*)&E[xi + j][yg * 8];
        float4 e1 = *(const float4*)&E[xi + j][yg * 8 + 4];
        float ev[8] = {e0.x, e0.y, e0.z, e0.w, e1.x, e1.y, e1.z, e1.w};
#pragma unroll
        for (int u = 0; u < 8; ++u) {
          float a = (j == 0) ? p[u].x : (j == 1) ? p[u].y : (j == 2) ? p[u].z : p[u].w;
#pragma unroll
          for (int v = 0; v < 8; ++v) acc[u][v] += a * ev[v];
        }
      }
    }
    __syncthreads();
  }
#pragma unroll
  for (int u = 0; u < 8; ++u) {
    int k = kg * 8 + u;
    float4 r0, r1;
    r0.x = acc[u][0]; r0.y = acc[u][1]; r0.z = acc[u][2]; r0.w = acc[u][3];
    r1.x = acc[u][4]; r1.y = acc[u][5]; r1.z = acc[u][6]; r1.w = acc[u][7];
    float* ob = out + ((size_t)b * CO + k) * HW + y0 + yg * 8;
    *(float4*)&ob[0] = r0;
    *(float4*)&ob[4] = r1;
  }
}

// ===========================================================================
extern "C" void kernel_launch(void* const* d_in, const int* in_sizes, int n_in,
                              void* d_out, int out_size, void* d_ws, size_t ws_size,
                              hipStream_t stream) {
  const float* x    = (const float*)d_in[0];
  const float* pem  = (const float*)d_in[1];
  const float* W    = (const float*)d_in[2];
  const float* bias = (const float*)d_in[3];
  float* out = (float*)d_out;

  const size_t NS = (size_t)BATCH * HW * CO;  // 8.39M elements
  const size_t need_mfma = NS * 2 * 5 + 2 * (size_t)BATCH * HW * 4;

  if (ws_size >= need_mfma) {
    ushort_t* proj_hi  = (ushort_t*)d_ws;
    ushort_t* proj_lo  = proj_hi + NS;
    ushort_t* pem_t_hi = proj_lo + NS;
    ushort_t* pem_t_lo = pem_t_hi + NS;
    ushort_t* pem_kx   = pem_t_lo + NS;
    float*    Mx       = (float*)(pem_kx + NS);
    float*    Dinv     = Mx + (size_t)BATCH * HW;

    k_proj_split<<<dim3(HW / 64, CO / 64, BATCH), 256, 0, stream>>>(
        x, W, bias, proj_hi, proj_lo);
    k_tr_pem<<<dim3(HW / 64, CO / 64, BATCH), 256, 0, stream>>>(
        pem, pem_t_hi, pem_t_lo, pem_kx);
    k_stats_mfma<<<dim3(512), 512, 0, stream>>>(
        proj_hi, proj_lo, pem_t_hi, pem_t_lo, Mx, Dinv);
    k_out_mfma<<<dim3(512), 512, 0, stream>>>(
        proj_hi, proj_lo, pem_t_hi, pem_t_lo, pem_kx, Mx, Dinv, out);
  } else {
    const size_t projElems = NS;
    float* proj = (float*)d_ws;
    float* Mx   = proj + projElems;
    float* Dinv = Mx + (size_t)BATCH * HW;
    const size_t need = (projElems + 2 * (size_t)BATCH * HW) * sizeof(float);
    if (ws_size < need) return;
    k_proj <<<dim3(HW / 64, CO / 64, BATCH), 256, 0, stream>>>(x, W, bias, proj);
    k_stats<<<dim3(HW / 64, BATCH),          256, 0, stream>>>(proj, pem, Mx, Dinv);
    k_out  <<<dim3(HW / 64, BATCH),          256, 0, stream>>>(proj, pem, Mx, Dinv, out);
  }
}